// Round 1
// 1491.149 us; speedup vs baseline: 2.0696x; 2.0696x over previous
//
#include <hip/hip_runtime.h>
#include <hip/hip_fp16.h>

typedef unsigned int u32;
typedef unsigned short u16;
typedef u32 __attribute__((may_alias)) u32a;
typedef u16 __attribute__((may_alias)) u16a;
typedef uint4 __attribute__((may_alias)) uint4a;
typedef float __attribute__((may_alias)) f32a;

typedef __attribute__((ext_vector_type(8))) short short8v;  // 8 bf16 (4 VGPRs)
typedef __attribute__((ext_vector_type(4))) float float4v;  // 4 f32 acc

union Frag { uint4 q; short8v s; u16 u[8]; };

#define BATCH 16
#define CIN   512
#define NPIX  4096
#define DD    64
#define VV    256
#define MM    1024

__device__ __forceinline__ float b2f(u16 u) {
  union { u32 i; float f; } v; v.i = ((u32)u) << 16; return v.f;
}
__device__ __forceinline__ u16 f2b(float f) {
  union { float f; u32 i; } v; v.f = f;
  u32 u = v.i;
  u32 r = (u + 0x7fffu + ((u >> 16) & 1u)) >> 16;
  return (u16)r;
}
__device__ __forceinline__ u16 f2h(float f) { return __half_as_ushort(__float2half(f)); }
__device__ __forceinline__ float h2f(u16 u) { return __half2float(__ushort_as_half(u)); }

// packed bf16x2 dot product, f32 accumulate — plain-fma version (k_proj still uses it)
__device__ __forceinline__ float dot2(u32 a, u32 b, float c) {
  union { u32 i; float f; } a0, a1, b0, b1;
  a0.i = a << 16; a1.i = a & 0xffff0000u;
  b0.i = b << 16; b1.i = b & 0xffff0000u;
  return fmaf(a1.f, b1.f, fmaf(a0.f, b0.f, c));
}

// ---------------------------------------------------------------------------
// K0a: input-dtype detection. meta[0] = 1 (inputs fp32) or 0 (inputs bf16).
// ---------------------------------------------------------------------------
__global__ __launch_bounds__(256) void k_detect(const void* __restrict__ x,
                                                u32* __restrict__ meta) {
  __shared__ int bad[256];
  const int t = threadIdx.x;
  float f = b2f(((const u16a*)x)[2 * t]);
  float a = fabsf(f);
  bad[t] = (a >= 1e-6f && a <= 100.f) ? 0 : 1;  // NaN -> bad (compares false)
  __syncthreads();
  if (t == 0) {
    int s = 0;
#pragma unroll 16
    for (int i = 0; i < 256; ++i) s += bad[i];
    meta[0] = (s > 64) ? 1u : 0u;
  }
}

// ---------------------------------------------------------------------------
// K0b: weights (+gamma) -> bf16 copy in ws.  wbf layout: wt@0, wp@32768,
// wg@65536, wo@196608 (u16 elements).  grid = 1280 x 256.
// ---------------------------------------------------------------------------
__global__ __launch_bounds__(256) void k_cvt(
    const void* __restrict__ wt, const void* __restrict__ wp,
    const void* __restrict__ wg, const void* __restrict__ wo,
    const void* __restrict__ gm, const u32* __restrict__ meta,
    u16* __restrict__ wbf, float* __restrict__ gout) {
  const int flag = (int)meta[0];
  const int i = blockIdx.x * 256 + threadIdx.x;
  const void* src; int j;
  if (i < 32768)       { src = wt; j = i; }
  else if (i < 65536)  { src = wp; j = i - 32768; }
  else if (i < 196608) { src = wg; j = i - 65536; }
  else                 { src = wo; j = i - 196608; }
  wbf[i] = flag ? f2b(((const f32a*)src)[j]) : ((const u16a*)src)[j];
  if (i == 0)
    gout[0] = flag ? ((const f32a*)gm)[0] : b2f(((const u16a*)gm)[0]);
}

// ---------------------------------------------------------------------------
// K1: theta/phi/g projections (1x1 convs) + fused 2x2 maxpool for phi,g.
// grid = 16 b * 32 yp * 4 og.  theta -> [b][d][n]; phi -> [b][m][d]; g -> [b][v][m]
// ---------------------------------------------------------------------------
__global__ __launch_bounds__(256) void k_proj(
    const void* __restrict__ x, const u16* __restrict__ wt,
    const u16* __restrict__ wp, const u16* __restrict__ wg,
    const u32* __restrict__ meta,
    u16* __restrict__ theta, u16* __restrict__ phi_t, u16* __restrict__ g)
{
  __shared__ __align__(16) u16 xs[128][134];
  const int tid  = threadIdx.x;
  const int lane = tid & 63;
  const int wv   = tid >> 6;
  const int blk  = blockIdx.x;
  const int b  = blk >> 7;
  const int yp = (blk >> 2) & 31;
  const int og = blk & 3;
  const int n0 = yp * 128;
  const int rbase = og * 96 + wv * 24;
  const int flag = (int)meta[0];

  float acc[24][2];
#pragma unroll
  for (int i = 0; i < 24; ++i) { acc[i][0] = 0.f; acc[i][1] = 0.f; }

  for (int cc = 0; cc < 4; ++cc) {
    const int c0 = cc * 128;
    __syncthreads();
    if (flag) {
#pragma unroll 8
      for (int it = 0; it < 64; ++it) {
        int idx = tid + it * 256;
        int cl = idx >> 7, px = idx & 127;
        xs[px][cl] = f2b(((const f32a*)x)[((size_t)(b * CIN + c0 + cl)) * NPIX + (n0 + px)]);
      }
    } else {
#pragma unroll 8
      for (int it = 0; it < 64; ++it) {
        int idx = tid + it * 256;
        int cl = idx >> 7, px = idx & 127;
        xs[px][cl] = ((const u16a*)x)[((size_t)(b * CIN + c0 + cl)) * NPIX + (n0 + px)];
      }
    }
    __syncthreads();
#pragma unroll
    for (int grp = 0; grp < 6; ++grp) {
      const int r0g = rbase + grp * 4;
      const u16* wr0; const u16* wr1; const u16* wr2; const u16* wr3;
      {
        int r = r0g;
        wr0 = (r < 64 ? wt + (size_t)r * CIN : (r < 128 ? wp + (size_t)(r-64) * CIN : wg + (size_t)(r-128) * CIN)) + c0;
        r = r0g + 1;
        wr1 = (r < 64 ? wt + (size_t)r * CIN : (r < 128 ? wp + (size_t)(r-64) * CIN : wg + (size_t)(r-128) * CIN)) + c0;
        r = r0g + 2;
        wr2 = (r < 64 ? wt + (size_t)r * CIN : (r < 128 ? wp + (size_t)(r-64) * CIN : wg + (size_t)(r-128) * CIN)) + c0;
        r = r0g + 3;
        wr3 = (r < 64 ? wt + (size_t)r * CIN : (r < 128 ? wp + (size_t)(r-64) * CIN : wg + (size_t)(r-128) * CIN)) + c0;
      }
#pragma unroll 2
      for (int cl = 0; cl < 128; cl += 8) {
        u32 xa0 = *(const u32a*)&xs[lane][cl];
        u32 xa1 = *(const u32a*)&xs[lane][cl + 2];
        u32 xa2 = *(const u32a*)&xs[lane][cl + 4];
        u32 xa3 = *(const u32a*)&xs[lane][cl + 6];
        u32 xb0 = *(const u32a*)&xs[lane + 64][cl];
        u32 xb1 = *(const u32a*)&xs[lane + 64][cl + 2];
        u32 xb2 = *(const u32a*)&xs[lane + 64][cl + 4];
        u32 xb3 = *(const u32a*)&xs[lane + 64][cl + 6];
        {
          uint4 w4 = *(const uint4a*)(wr0 + cl);
          acc[grp*4+0][0] = dot2(xa0, w4.x, acc[grp*4+0][0]);
          acc[grp*4+0][0] = dot2(xa1, w4.y, acc[grp*4+0][0]);
          acc[grp*4+0][0] = dot2(xa2, w4.z, acc[grp*4+0][0]);
          acc[grp*4+0][0] = dot2(xa3, w4.w, acc[grp*4+0][0]);
          acc[grp*4+0][1] = dot2(xb0, w4.x, acc[grp*4+0][1]);
          acc[grp*4+0][1] = dot2(xb1, w4.y, acc[grp*4+0][1]);
          acc[grp*4+0][1] = dot2(xb2, w4.z, acc[grp*4+0][1]);
          acc[grp*4+0][1] = dot2(xb3, w4.w, acc[grp*4+0][1]);
        }
        {
          uint4 w4 = *(const uint4a*)(wr1 + cl);
          acc[grp*4+1][0] = dot2(xa0, w4.x, acc[grp*4+1][0]);
          acc[grp*4+1][0] = dot2(xa1, w4.y, acc[grp*4+1][0]);
          acc[grp*4+1][0] = dot2(xa2, w4.z, acc[grp*4+1][0]);
          acc[grp*4+1][0] = dot2(xa3, w4.w, acc[grp*4+1][0]);
          acc[grp*4+1][1] = dot2(xb0, w4.x, acc[grp*4+1][1]);
          acc[grp*4+1][1] = dot2(xb1, w4.y, acc[grp*4+1][1]);
          acc[grp*4+1][1] = dot2(xb2, w4.z, acc[grp*4+1][1]);
          acc[grp*4+1][1] = dot2(xb3, w4.w, acc[grp*4+1][1]);
        }
        {
          uint4 w4 = *(const uint4a*)(wr2 + cl);
          acc[grp*4+2][0] = dot2(xa0, w4.x, acc[grp*4+2][0]);
          acc[grp*4+2][0] = dot2(xa1, w4.y, acc[grp*4+2][0]);
          acc[grp*4+2][0] = dot2(xa2, w4.z, acc[grp*4+2][0]);
          acc[grp*4+2][0] = dot2(xa3, w4.w, acc[grp*4+2][0]);
          acc[grp*4+2][1] = dot2(xb0, w4.x, acc[grp*4+2][1]);
          acc[grp*4+2][1] = dot2(xb1, w4.y, acc[grp*4+2][1]);
          acc[grp*4+2][1] = dot2(xb2, w4.z, acc[grp*4+2][1]);
          acc[grp*4+2][1] = dot2(xb3, w4.w, acc[grp*4+2][1]);
        }
        {
          uint4 w4 = *(const uint4a*)(wr3 + cl);
          acc[grp*4+3][0] = dot2(xa0, w4.x, acc[grp*4+3][0]);
          acc[grp*4+3][0] = dot2(xa1, w4.y, acc[grp*4+3][0]);
          acc[grp*4+3][0] = dot2(xa2, w4.z, acc[grp*4+3][0]);
          acc[grp*4+3][0] = dot2(xa3, w4.w, acc[grp*4+3][0]);
          acc[grp*4+3][1] = dot2(xb0, w4.x, acc[grp*4+3][1]);
          acc[grp*4+3][1] = dot2(xb1, w4.y, acc[grp*4+3][1]);
          acc[grp*4+3][1] = dot2(xb2, w4.z, acc[grp*4+3][1]);
          acc[grp*4+3][1] = dot2(xb3, w4.w, acc[grp*4+3][1]);
        }
      }
    }
  }

  // epilogue: theta direct, phi/g with 2x2 maxpool
#pragma unroll
  for (int grp = 0; grp < 6; ++grp) {
#pragma unroll
    for (int k = 0; k < 4; ++k) {
      const int r = rbase + grp * 4 + k;
      float a0 = acc[grp*4+k][0], a1 = acc[grp*4+k][1];
      if (r < 64) {
        theta[((size_t)(b * DD + r)) * NPIX + n0 + lane]      = f2b(a0);
        theta[((size_t)(b * DD + r)) * NPIX + n0 + 64 + lane] = f2b(a1);
      } else {
        float pm = fmaxf(a0, a1);                 // max over 2 spatial rows
        float po = fmaxf(pm, __shfl_xor(pm, 1));  // max over col pair
        if (!(lane & 1)) {
          int m = yp * 32 + (lane >> 1);
          if (r < 128) phi_t[((size_t)(b * MM + m)) * DD + (r - 64)] = f2b(po);
          else         g[((size_t)(b * VV + (r - 128))) * MM + m]    = f2b(po);
        }
      }
    }
  }
}

// ---------------------------------------------------------------------------
// K2 (MFMA rewrite): fused attention + output projection + residual.
// grid = 16 b * 256 qtiles of 16 queries, 256 threads (4 waves).
//   pass1: S[16q][1024m] via mfma_f32_16x16x32_bf16, waves split m. -> LDS fp16
//   pass2: softmax over m, in-place repack exp() to bf16 pairs.
//   pass3: o[v][q] = g . P^T via MFMA, waves split v (64 each). -> o^T LDS
//   pass4: out = gamma * (wo . o) + x via MFMA, waves split oc (128 each).
// Fragment maps (verified gfx950): A row = lane&15, k = (lane>>4)*8+i;
// B col = lane&15, k = (lane>>4)*8+i; C col = lane&15, row = (lane>>4)*4+reg.
// sc row stride 516 dwords (pad) -> LDS bank shift 4/row -> <=2-way conflicts.
// ---------------------------------------------------------------------------
__global__ __launch_bounds__(256) void k_attn(
    const u16* __restrict__ theta, const u16* __restrict__ phi_t,
    const u16* __restrict__ g, const u16* __restrict__ wo,
    const void* __restrict__ x, const float* __restrict__ gamma_p,
    const u32* __restrict__ meta, void* __restrict__ out)
{
  __shared__ __align__(16) u32 sc[16 * 516];   // fp16 scores -> exp'd bf16 pairs (rows padded 1024->1032 u16)
  __shared__ __align__(16) u16 ot[16 * 264];   // o^T [q][v], v-row padded 256->264
  __shared__ float pmax[16][16];
  __shared__ float psum[16][16];
  __shared__ float sinv_s[16];

  const int tid  = threadIdx.x;
  const int lane = tid & 63;
  const int wv   = tid >> 6;       // wave id 0..3
  const int lg   = lane >> 4;      // lane-group 0..3 (k dimension)
  const int lr   = lane & 15;      // row/col within fragment
  const int blk  = blockIdx.x;
  const int b    = blk >> 8;
  const int qt   = blk & 255;
  const int nq0  = qt * 16;
  const int flag = (int)meta[0];

  u16a* sc16 = (u16a*)sc;

  // ---- Q fragments (A operand), gathered once per block (per-wave copy) ----
  short8v qa[2];
#pragma unroll
  for (int kk = 0; kk < 2; ++kk) {
    Frag f;
#pragma unroll
    for (int i = 0; i < 8; ++i) {
      int d = kk * 32 + lg * 8 + i;
      f.u[i] = theta[((size_t)(b * DD + d)) * NPIX + nq0 + lr];
    }
    qa[kk] = f.s;
  }

  // ---- pass 1: scores; wave w owns m in [w*256, w*256+256) ----
  {
    const u16* pt = phi_t + (size_t)b * (MM * DD);
#pragma unroll 2
    for (int mt = 0; mt < 16; ++mt) {
      const int m0 = wv * 256 + mt * 16;
      float4v s = {0.f, 0.f, 0.f, 0.f};
#pragma unroll
      for (int kk = 0; kk < 2; ++kk) {
        Frag f; f.q = *(const uint4a*)(pt + (size_t)(m0 + lr) * DD + kk * 32 + lg * 8);
        s = __builtin_amdgcn_mfma_f32_16x16x32_bf16(qa[kk], f.s, s, 0, 0, 0);
      }
#pragma unroll
      for (int r = 0; r < 4; ++r) {
        int qq = lg * 4 + r;
        float v = fminf(fmaxf(s[r], -6.0e4f), 6.0e4f);  // fp16-safe clamp
        sc16[qq * 1032 + m0 + lr] = f2h(v);
      }
    }
  }
  __syncthreads();

  // ---- pass 2: max, exp, sum; in-place repack to bf16 pairs ----
  {
    const int q  = tid & 15;
    const int sg = tid >> 4;    // 16 segments x 64 m
    float mx = -3.0e38f;
#pragma unroll 8
    for (int k = 0; k < 64; ++k) {
      int kk = (k + sg * 2) & 63;   // rotate to dodge bank collisions
      mx = fmaxf(mx, h2f(sc16[q * 1032 + sg * 64 + kk]));
    }
    pmax[q][sg] = mx;
    __syncthreads();
    float maxq = -3.0e38f;
#pragma unroll
    for (int i = 0; i < 16; ++i) maxq = fmaxf(maxq, pmax[q][i]);
    float ssum = 0.f;
#pragma unroll 4
    for (int kp = 0; kp < 32; ++kp) {
      int kk = (kp + sg) & 31;
      int idx = q * 516 + sg * 32 + kk;
      u32 raw = sc[idx];
      float f0 = h2f((u16)(raw & 0xffffu));
      float f1 = h2f((u16)(raw >> 16));
      float e0 = __expf(fminf(f0 - maxq, 0.f));
      float e1 = __expf(fminf(f1 - maxq, 0.f));
      ssum += e0 + e1;
      sc[idx] = (u32)f2b(e0) | ((u32)f2b(e1) << 16);
    }
    psum[q][sg] = ssum;
    __syncthreads();
    float tot = 0.f;
#pragma unroll
    for (int i = 0; i < 16; ++i) tot += psum[q][i];
    if (sg == 0) sinv_s[q] = 1.f / tot;
  }
  __syncthreads();

  // ---- pass 3: o[v][q] = sum_m g[v][m] P[q][m]; wave owns v in [wv*64, +64) ----
  {
    float4v oacc[4];
#pragma unroll
    for (int i = 0; i < 4; ++i) oacc[i] = (float4v){0.f, 0.f, 0.f, 0.f};
    const u16* gb = g + (size_t)b * (VV * MM);
#pragma unroll 2
    for (int ms = 0; ms < 32; ++ms) {
      Frag pf; pf.q = *(const uint4a*)(sc16 + lr * 1032 + ms * 32 + lg * 8);  // B = P^T
#pragma unroll
      for (int vt = 0; vt < 4; ++vt) {
        Frag gf; gf.q = *(const uint4a*)(gb + (size_t)(wv * 64 + vt * 16 + lr) * MM + ms * 32 + lg * 8);
        oacc[vt] = __builtin_amdgcn_mfma_f32_16x16x32_bf16(gf.s, pf.s, oacc[vt], 0, 0, 0);
      }
    }
    const float si = sinv_s[lr];   // softmax denominator for this q column
#pragma unroll
    for (int vt = 0; vt < 4; ++vt) {
      u32 lo = (u32)f2b(oacc[vt][0] * si) | ((u32)f2b(oacc[vt][1] * si) << 16);
      u32 hi = (u32)f2b(oacc[vt][2] * si) | ((u32)f2b(oacc[vt][3] * si) << 16);
      u32a* p = (u32a*)&ot[lr * 264 + wv * 64 + vt * 16 + lg * 4];
      p[0] = lo; p[1] = hi;
    }
  }
  __syncthreads();

  // ---- pass 4: out = gamma*(wo . o) + x; wave owns oc in [wv*128, +128) ----
  {
    short8v ob[8];
#pragma unroll
    for (int ks = 0; ks < 8; ++ks) {    // hoist B frags (o^T), K = 256 v
      Frag f; f.q = *(const uint4a*)(ot + lr * 264 + ks * 32 + lg * 8);
      ob[ks] = f.s;
    }
    const float gmv = gamma_p[0];
    const int oc0 = wv * 128;
#pragma unroll 2
    for (int oct = 0; oct < 8; ++oct) {
      float4v c = {0.f, 0.f, 0.f, 0.f};
#pragma unroll
      for (int ks = 0; ks < 8; ++ks) {
        Frag f; f.q = *(const uint4a*)(wo + (size_t)(oc0 + oct * 16 + lr) * VV + ks * 32 + lg * 8);
        c = __builtin_amdgcn_mfma_f32_16x16x32_bf16(f.s, ob[ks], c, 0, 0, 0);
      }
#pragma unroll
      for (int r = 0; r < 4; ++r) {
        int oc = oc0 + oct * 16 + lg * 4 + r;
        size_t off = ((size_t)(b * CIN + oc)) * NPIX + nq0 + lr;
        if (flag) {
          ((f32a*)out)[off] = gmv * c[r] + ((const f32a*)x)[off];     // fp32 world
        } else {
          ((u16a*)out)[off] = f2b(gmv * c[r] + b2f(((const u16a*)x)[off]));  // bf16 world
        }
      }
    }
  }
}

extern "C" void kernel_launch(void* const* d_in, const int* in_sizes, int n_in,
                              void* d_out, int out_size, void* d_ws, size_t ws_size,
                              hipStream_t stream) {
  (void)in_sizes; (void)n_in; (void)out_size; (void)ws_size;
  const void* x  = d_in[0];
  const void* wt = d_in[1];
  const void* wp = d_in[2];
  const void* wg = d_in[3];
  const void* wo = d_in[4];
  const void* gm = d_in[5];

  u16* theta = (u16*)d_ws;                              // [16][64][4096]  bf16
  u16* phi_t = theta + (size_t)BATCH * DD * NPIX;       // [16][1024][64]  bf16 (transposed)
  u16* g     = phi_t + (size_t)BATCH * MM * DD;         // [16][256][1024] bf16
  u16* wbf   = g     + (size_t)BATCH * VV * MM;         // 327680 bf16 weights
  float* gamma_f = (float*)(wbf + 327680);              // converted gamma
  u32* meta      = (u32*)(gamma_f + 1);                 // dtype flag

  hipLaunchKernelGGL(k_detect, dim3(1), dim3(256), 0, stream, x, meta);
  hipLaunchKernelGGL(k_cvt, dim3(1280), dim3(256), 0, stream,
                     wt, wp, wg, wo, gm, meta, wbf, gamma_f);
  hipLaunchKernelGGL(k_proj, dim3(BATCH * 32 * 4), dim3(256), 0, stream,
                     x, wbf, wbf + 32768, wbf + 65536, meta, theta, phi_t, g);
  hipLaunchKernelGGL(k_attn, dim3(BATCH * 256), dim3(256), 0, stream,
                     theta, phi_t, g, wbf + 196608, x, gamma_f, meta, d_out);
}

// Round 2
// 754.801 us; speedup vs baseline: 4.0886x; 1.9756x over previous
//
#include <hip/hip_runtime.h>
#include <hip/hip_fp16.h>

typedef unsigned int u32;
typedef unsigned short u16;
typedef u32 __attribute__((may_alias)) u32a;
typedef u16 __attribute__((may_alias)) u16a;
typedef uint4 __attribute__((may_alias)) uint4a;
typedef uint2 __attribute__((may_alias)) uint2a;
typedef float __attribute__((may_alias)) f32a;
typedef float4 __attribute__((may_alias)) float4a;

typedef __attribute__((ext_vector_type(8))) short short8v;  // 8 bf16 (4 VGPRs)
typedef __attribute__((ext_vector_type(4))) float float4v;  // 4 f32 acc

union Frag { uint4 q; short8v s; u16 u[8]; };
union F4 { float4 v; float f[4]; };

#define BATCH 16
#define CIN   512
#define NPIX  4096
#define DD    64
#define VV    256
#define MM    1024

__device__ __forceinline__ float b2f(u16 u) {
  union { u32 i; float f; } v; v.i = ((u32)u) << 16; return v.f;
}
__device__ __forceinline__ u16 f2b(float f) {
  union { float f; u32 i; } v; v.f = f;
  u32 u = v.i;
  u32 r = (u + 0x7fffu + ((u >> 16) & 1u)) >> 16;
  return (u16)r;
}
__device__ __forceinline__ u16 f2h(float f) { return __half_as_ushort(__float2half(f)); }
__device__ __forceinline__ float h2f(u16 u) { return __half2float(__ushort_as_half(u)); }

// packed RNE f32x2 -> bf16x2 (hardware cvt; same rounding as f2b)
__device__ __forceinline__ u32 cvtpk(float lo, float hi) {
  u32 r;
  asm("v_cvt_pk_bf16_f32 %0, %1, %2" : "=v"(r) : "v"(lo), "v"(hi));
  return r;
}

// packed bf16x2 dot product, f32 accumulate
__device__ __forceinline__ float dot2(u32 a, u32 b, float c) {
  union { u32 i; float f; } a0, a1, b0, b1;
  a0.i = a << 16; a1.i = a & 0xffff0000u;
  b0.i = b << 16; b1.i = b & 0xffff0000u;
  return fmaf(a1.f, b1.f, fmaf(a0.f, b0.f, c));
}

// ---------------------------------------------------------------------------
// K0a: input-dtype detection. meta[0] = 1 (inputs fp32) or 0 (inputs bf16).
// ---------------------------------------------------------------------------
__global__ __launch_bounds__(256) void k_detect(const void* __restrict__ x,
                                                u32* __restrict__ meta) {
  __shared__ int bad[256];
  const int t = threadIdx.x;
  float f = b2f(((const u16a*)x)[2 * t]);
  float a = fabsf(f);
  bad[t] = (a >= 1e-6f && a <= 100.f) ? 0 : 1;  // NaN -> bad (compares false)
  __syncthreads();
  if (t == 0) {
    int s = 0;
#pragma unroll 16
    for (int i = 0; i < 256; ++i) s += bad[i];
    meta[0] = (s > 64) ? 1u : 0u;
  }
}

// ---------------------------------------------------------------------------
// K0b: weights (+gamma) -> bf16 copy in ws.  wbf layout: wt@0, wp@32768,
// wg@65536, wo@196608 (u16 elements).  grid = 1280 x 256.
// ---------------------------------------------------------------------------
__global__ __launch_bounds__(256) void k_cvt(
    const void* __restrict__ wt, const void* __restrict__ wp,
    const void* __restrict__ wg, const void* __restrict__ wo,
    const void* __restrict__ gm, const u32* __restrict__ meta,
    u16* __restrict__ wbf, float* __restrict__ gout) {
  const int flag = (int)meta[0];
  const int i = blockIdx.x * 256 + threadIdx.x;
  const void* src; int j;
  if (i < 32768)       { src = wt; j = i; }
  else if (i < 65536)  { src = wp; j = i - 32768; }
  else if (i < 196608) { src = wg; j = i - 65536; }
  else                 { src = wo; j = i - 196608; }
  wbf[i] = flag ? f2b(((const f32a*)src)[j]) : ((const u16a*)src)[j];
  if (i == 0)
    gout[0] = flag ? ((const f32a*)gm)[0] : b2f(((const u16a*)gm)[0]);
}

// ---------------------------------------------------------------------------
// K1 (MFMA rewrite): theta/phi/g projections + fused 2x2 maxpool for phi,g.
// grid = 16 b * 32 pxt (128 px = 2 image rows each), 256 threads (4 waves).
// Rows 0..383 of W are contiguous in wbf (wt,wp,wg back-to-back).
// Wave w owns rows [w*96, w*96+96) x all 128 px: acc[6 rt][8 pt] f32x4.
// x tile staged transposed [px][c] in LDS (bf16), stride 136 u16 (16B align).
//   theta -> [b][d][n]; phi -> [b][m][d]; g -> [b][v][m]  (unchanged layouts)
// ---------------------------------------------------------------------------
__global__ __launch_bounds__(256) void k_proj(
    const void* __restrict__ x, const u16* __restrict__ w_all,
    const u32* __restrict__ meta,
    u16* __restrict__ theta, u16* __restrict__ phi_t, u16* __restrict__ g)
{
  __shared__ __align__(16) u16 xs[128][136];
  const int tid  = threadIdx.x;
  const int lane = tid & 63;
  const int wv   = tid >> 6;
  const int lg   = lane >> 4;      // k-group 0..3
  const int lr   = lane & 15;      // row/col within fragment
  const int blk  = blockIdx.x;
  const int b    = blk >> 5;
  const int pxt  = blk & 31;
  const int n0   = pxt * 128;      // 2 image rows y0=2*pxt, y0+1
  const int rbase = wv * 96;
  const int flag = (int)meta[0];

  float4v acc[6][8];
#pragma unroll
  for (int i = 0; i < 6; ++i)
#pragma unroll
    for (int j = 0; j < 8; ++j) acc[i][j] = (float4v){0.f, 0.f, 0.f, 0.f};

  // staging assignment: thread -> (4 px in each image row half, 8 channels)
  const int pg = tid & 15;         // px quad: [pg*4, pg*4+4) and +64
  const int cg = tid >> 4;         // channel octet: [cg*8, cg*8+8)

  for (int cc = 0; cc < 4; ++cc) {
    const int c0 = cc * 128;
    __syncthreads();
    if (flag) {
      // fp32 path: coalesced float4 loads, packed cvt to bf16, b64 LDS writes
      const f32a* src = (const f32a*)x +
          ((size_t)(b * CIN + c0 + cg * 8)) * NPIX + n0 + pg * 4;
#pragma unroll
      for (int cq = 0; cq < 2; ++cq) {        // two channel-quads
        const f32a* s4 = src + (size_t)(cq * 4) * NPIX;
        F4 a0, a1, a2, a3, b0, b1, b2, b3;
        a0.v = *(const float4a*)(s4);
        b0.v = *(const float4a*)(s4 + 64);
        a1.v = *(const float4a*)(s4 + NPIX);
        b1.v = *(const float4a*)(s4 + NPIX + 64);
        a2.v = *(const float4a*)(s4 + 2 * (size_t)NPIX);
        b2.v = *(const float4a*)(s4 + 2 * (size_t)NPIX + 64);
        a3.v = *(const float4a*)(s4 + 3 * (size_t)NPIX);
        b3.v = *(const float4a*)(s4 + 3 * (size_t)NPIX + 64);
        const int colb = cg * 8 + cq * 4;
#pragma unroll
        for (int j = 0; j < 4; ++j) {
          uint2 wd; wd.x = cvtpk(a0.f[j], a1.f[j]); wd.y = cvtpk(a2.f[j], a3.f[j]);
          *(uint2a*)&xs[pg * 4 + j][colb] = wd;
          uint2 vd; vd.x = cvtpk(b0.f[j], b1.f[j]); vd.y = cvtpk(b2.f[j], b3.f[j]);
          *(uint2a*)&xs[64 + pg * 4 + j][colb] = vd;
        }
      }
    } else {
      // bf16 path (correctness fallback; not hit in this bench): scalar scatter
#pragma unroll 8
      for (int it = 0; it < 64; ++it) {
        int idx = tid + it * 256;
        int cl = idx >> 7, px = idx & 127;
        xs[px][cl] = ((const u16a*)x)[((size_t)(b * CIN + c0 + cl)) * NPIX + (n0 + px)];
      }
    }
    __syncthreads();

#pragma unroll
    for (int kk = 0; kk < 4; ++kk) {
      // hoist the 8 B-fragments (x tile) for this k-slice
      short8v bfr[8];
#pragma unroll
      for (int pt = 0; pt < 8; ++pt) {
        Frag f; f.q = *(const uint4a*)&xs[pt * 16 + lr][kk * 32 + lg * 8];
        bfr[pt] = f.s;
      }
      // stream A-fragments (weights, L2-resident) and MFMA
#pragma unroll
      for (int rt = 0; rt < 6; ++rt) {
        Frag af;
        af.q = *(const uint4a*)(w_all +
            (size_t)(rbase + rt * 16 + lr) * CIN + c0 + kk * 32 + lg * 8);
#pragma unroll
        for (int pt = 0; pt < 8; ++pt)
          acc[rt][pt] = __builtin_amdgcn_mfma_f32_16x16x32_bf16(af.s, bfr[pt], acc[rt][pt], 0, 0, 0);
      }
    }
  }

  // epilogue: theta direct; phi/g with 2x2 maxpool.
  // C layout: px col = n0 + pt*16 + lr; row = rbase + rt*16 + lg*4 + r.
#pragma unroll
  for (int rt = 0; rt < 6; ++rt) {
    const int rowb = rbase + rt * 16;
    if (rowb < 64) {
      // theta rows (wave 0, rt 0..3)
#pragma unroll
      for (int pt = 0; pt < 8; ++pt)
#pragma unroll
        for (int r = 0; r < 4; ++r) {
          int row = rowb + lg * 4 + r;
          theta[((size_t)(b * DD + row)) * NPIX + n0 + pt * 16 + lr] = f2b(acc[rt][pt][r]);
        }
    } else {
      // phi (rows 64..127) or g (rows 128..383), pooled 2x2:
      // px pairs (pt, pt+4) are image rows y0,y0+1; lr pairs are col pairs.
#pragma unroll
      for (int pt = 0; pt < 4; ++pt)
#pragma unroll
        for (int r = 0; r < 4; ++r) {
          int row = rowb + lg * 4 + r;
          float pm = fmaxf(acc[rt][pt][r], acc[rt][pt + 4][r]);
          float po = fmaxf(pm, __shfl_xor(pm, 1));
          if (!(lr & 1)) {
            int m = pxt * 32 + pt * 8 + (lr >> 1);
            if (row < 128) phi_t[((size_t)(b * MM + m)) * DD + (row - 64)] = f2b(po);
            else           g[((size_t)(b * VV + (row - 128))) * MM + m]    = f2b(po);
          }
        }
    }
  }
}

// ---------------------------------------------------------------------------
// K2 (MFMA): fused attention + output projection + residual.
// grid = 16 b * 256 qtiles of 16 queries, 256 threads (4 waves).
// ---------------------------------------------------------------------------
__global__ __launch_bounds__(256) void k_attn(
    const u16* __restrict__ theta, const u16* __restrict__ phi_t,
    const u16* __restrict__ g, const u16* __restrict__ wo,
    const void* __restrict__ x, const float* __restrict__ gamma_p,
    const u32* __restrict__ meta, void* __restrict__ out)
{
  __shared__ __align__(16) u32 sc[16 * 516];   // fp16 scores -> exp'd bf16 pairs (rows padded 1024->1032 u16)
  __shared__ __align__(16) u16 ot[16 * 264];   // o^T [q][v], v-row padded 256->264
  __shared__ float pmax[16][16];
  __shared__ float psum[16][16];
  __shared__ float sinv_s[16];

  const int tid  = threadIdx.x;
  const int lane = tid & 63;
  const int wv   = tid >> 6;       // wave id 0..3
  const int lg   = lane >> 4;      // lane-group 0..3 (k dimension)
  const int lr   = lane & 15;      // row/col within fragment
  const int blk  = blockIdx.x;
  const int b    = blk >> 8;
  const int qt   = blk & 255;
  const int nq0  = qt * 16;
  const int flag = (int)meta[0];

  u16a* sc16 = (u16a*)sc;

  // ---- Q fragments (A operand), gathered once per block (per-wave copy) ----
  short8v qa[2];
#pragma unroll
  for (int kk = 0; kk < 2; ++kk) {
    Frag f;
#pragma unroll
    for (int i = 0; i < 8; ++i) {
      int d = kk * 32 + lg * 8 + i;
      f.u[i] = theta[((size_t)(b * DD + d)) * NPIX + nq0 + lr];
    }
    qa[kk] = f.s;
  }

  // ---- pass 1: scores; wave w owns m in [w*256, w*256+256) ----
  {
    const u16* pt = phi_t + (size_t)b * (MM * DD);
#pragma unroll 2
    for (int mt = 0; mt < 16; ++mt) {
      const int m0 = wv * 256 + mt * 16;
      float4v s = {0.f, 0.f, 0.f, 0.f};
#pragma unroll
      for (int kk = 0; kk < 2; ++kk) {
        Frag f; f.q = *(const uint4a*)(pt + (size_t)(m0 + lr) * DD + kk * 32 + lg * 8);
        s = __builtin_amdgcn_mfma_f32_16x16x32_bf16(qa[kk], f.s, s, 0, 0, 0);
      }
#pragma unroll
      for (int r = 0; r < 4; ++r) {
        int qq = lg * 4 + r;
        float v = fminf(fmaxf(s[r], -6.0e4f), 6.0e4f);  // fp16-safe clamp
        sc16[qq * 1032 + m0 + lr] = f2h(v);
      }
    }
  }
  __syncthreads();

  // ---- pass 2: max, exp, sum; in-place repack to bf16 pairs ----
  {
    const int q  = tid & 15;
    const int sg = tid >> 4;    // 16 segments x 64 m
    float mx = -3.0e38f;
#pragma unroll 8
    for (int k = 0; k < 64; ++k) {
      int kk = (k + sg * 2) & 63;   // rotate to dodge bank collisions
      mx = fmaxf(mx, h2f(sc16[q * 1032 + sg * 64 + kk]));
    }
    pmax[q][sg] = mx;
    __syncthreads();
    float maxq = -3.0e38f;
#pragma unroll
    for (int i = 0; i < 16; ++i) maxq = fmaxf(maxq, pmax[q][i]);
    float ssum = 0.f;
#pragma unroll 4
    for (int kp = 0; kp < 32; ++kp) {
      int kk = (kp + sg) & 31;
      int idx = q * 516 + sg * 32 + kk;
      u32 raw = sc[idx];
      float f0 = h2f((u16)(raw & 0xffffu));
      float f1 = h2f((u16)(raw >> 16));
      float e0 = __expf(fminf(f0 - maxq, 0.f));
      float e1 = __expf(fminf(f1 - maxq, 0.f));
      ssum += e0 + e1;
      sc[idx] = (u32)f2b(e0) | ((u32)f2b(e1) << 16);
    }
    psum[q][sg] = ssum;
    __syncthreads();
    float tot = 0.f;
#pragma unroll
    for (int i = 0; i < 16; ++i) tot += psum[q][i];
    if (sg == 0) sinv_s[q] = 1.f / tot;
  }
  __syncthreads();

  // ---- pass 3: o[v][q] = sum_m g[v][m] P[q][m]; wave owns v in [wv*64, +64) ----
  {
    float4v oacc[4];
#pragma unroll
    for (int i = 0; i < 4; ++i) oacc[i] = (float4v){0.f, 0.f, 0.f, 0.f};
    const u16* gb = g + (size_t)b * (VV * MM);
#pragma unroll 2
    for (int ms = 0; ms < 32; ++ms) {
      Frag pf; pf.q = *(const uint4a*)(sc16 + lr * 1032 + ms * 32 + lg * 8);  // B = P^T
#pragma unroll
      for (int vt = 0; vt < 4; ++vt) {
        Frag gf; gf.q = *(const uint4a*)(gb + (size_t)(wv * 64 + vt * 16 + lr) * MM + ms * 32 + lg * 8);
        oacc[vt] = __builtin_amdgcn_mfma_f32_16x16x32_bf16(gf.s, pf.s, oacc[vt], 0, 0, 0);
      }
    }
    const float si = sinv_s[lr];   // softmax denominator for this q column
#pragma unroll
    for (int vt = 0; vt < 4; ++vt) {
      u32 lo = (u32)f2b(oacc[vt][0] * si) | ((u32)f2b(oacc[vt][1] * si) << 16);
      u32 hi = (u32)f2b(oacc[vt][2] * si) | ((u32)f2b(oacc[vt][3] * si) << 16);
      u32a* p = (u32a*)&ot[lr * 264 + wv * 64 + vt * 16 + lg * 4];
      p[0] = lo; p[1] = hi;
    }
  }
  __syncthreads();

  // ---- pass 4: out = gamma*(wo . o) + x; wave owns oc in [wv*128, +128) ----
  {
    short8v ob[8];
#pragma unroll
    for (int ks = 0; ks < 8; ++ks) {    // hoist B frags (o^T), K = 256 v
      Frag f; f.q = *(const uint4a*)(ot + lr * 264 + ks * 32 + lg * 8);
      ob[ks] = f.s;
    }
    const float gmv = gamma_p[0];
    const int oc0 = wv * 128;
#pragma unroll 2
    for (int oct = 0; oct < 8; ++oct) {
      float4v c = {0.f, 0.f, 0.f, 0.f};
#pragma unroll
      for (int ks = 0; ks < 8; ++ks) {
        Frag f; f.q = *(const uint4a*)(wo + (size_t)(oc0 + oct * 16 + lr) * VV + ks * 32 + lg * 8);
        c = __builtin_amdgcn_mfma_f32_16x16x32_bf16(f.s, ob[ks], c, 0, 0, 0);
      }
#pragma unroll
      for (int r = 0; r < 4; ++r) {
        int oc = oc0 + oct * 16 + lg * 4 + r;
        size_t off = ((size_t)(b * CIN + oc)) * NPIX + nq0 + lr;
        if (flag) {
          ((f32a*)out)[off] = gmv * c[r] + ((const f32a*)x)[off];     // fp32 world
        } else {
          ((u16a*)out)[off] = f2b(gmv * c[r] + b2f(((const u16a*)x)[off]));  // bf16 world
        }
      }
    }
  }
}

extern "C" void kernel_launch(void* const* d_in, const int* in_sizes, int n_in,
                              void* d_out, int out_size, void* d_ws, size_t ws_size,
                              hipStream_t stream) {
  (void)in_sizes; (void)n_in; (void)out_size; (void)ws_size;
  const void* x  = d_in[0];
  const void* wt = d_in[1];
  const void* wp = d_in[2];
  const void* wg = d_in[3];
  const void* wo = d_in[4];
  const void* gm = d_in[5];

  u16* theta = (u16*)d_ws;                              // [16][64][4096]  bf16
  u16* phi_t = theta + (size_t)BATCH * DD * NPIX;       // [16][1024][64]  bf16 (transposed)
  u16* g     = phi_t + (size_t)BATCH * MM * DD;         // [16][256][1024] bf16
  u16* wbf   = g     + (size_t)BATCH * VV * MM;         // 327680 bf16 weights (wt|wp|wg|wo)
  float* gamma_f = (float*)(wbf + 327680);              // converted gamma
  u32* meta      = (u32*)(gamma_f + 1);                 // dtype flag

  hipLaunchKernelGGL(k_detect, dim3(1), dim3(256), 0, stream, x, meta);
  hipLaunchKernelGGL(k_cvt, dim3(1280), dim3(256), 0, stream,
                     wt, wp, wg, wo, gm, meta, wbf, gamma_f);
  hipLaunchKernelGGL(k_proj, dim3(BATCH * 32), dim3(256), 0, stream,
                     x, wbf, meta, theta, phi_t, g);
  hipLaunchKernelGGL(k_attn, dim3(BATCH * 256), dim3(256), 0, stream,
                     theta, phi_t, g, wbf + 196608, x, gamma_f, meta, d_out);
}